// Round 1
// baseline (493.858 us; speedup 1.0000x reference)
//
#include <hip/hip_runtime.h>
#include <stdint.h>

// GAT layer, N=8192, D_IN=512, D_OUT=64.
// k1: Wh = h@W (f32), writes Wh in bf16 *MFMA-B-fragment order*, plus Wh1=Wh@a1, Wh2=Wh@a2 (f32).
// k2: fused masked-softmax attention. Unnormalized p = exp(leakyrelu(Wh1[i]+Wh2[j])) (masked -> 0);
//     PV via mfma_f32_16x16x32_bf16; per-(rowblock, j-split) partial (acc, l) to ws.
// k3: out = elu(sum_acc / sum_l).
// Softmax shift-invariance: scores bounded (|s| <~ 10) so exp(s) is safe in f32 without
// max subtraction -> partials combine by pure addition across j-splits.

constexpr int NN = 8192;
constexpr int DIN = 512;
constexpr int DOUT = 64;
constexpr int NSPLIT = 8;
constexpr int JCHUNK = NN / NSPLIT;     // 1024 columns per block
constexpr int CTILE = 64;               // j-tile
constexpr int NTILES = JCHUNK / CTILE;  // 16

typedef __attribute__((ext_vector_type(4))) float f32x4;
typedef __attribute__((ext_vector_type(8))) short short8;

__device__ __forceinline__ unsigned short f2bf(float x) {
  union { float f; uint32_t u; } v; v.f = x;
  return (unsigned short)((v.u + 0x7fffu + ((v.u >> 16) & 1u)) >> 16);
}

// fragment-order byte offset for element (row c in K-dim, col d) of the B operand store.
// k-map (shared by A and B by construction): k = g*4 + (i&3) + 16*(i>>2), lane = g*16 + (d&15).
// byte = (c>>5)*4096 + (d>>4)*1024 + lane*16 + i*2
__device__ __forceinline__ int frag_byte(int c, int d) {
  int g = (c >> 2) & 3;
  int i = (c & 3) | (((c >> 4) & 1) << 2);
  return ((c >> 5) << 12) | ((d >> 4) << 10) | (((g << 4) | (d & 15)) << 4) | (i << 1);
}

__global__ __launch_bounds__(256) void k1_wh(
    const float* __restrict__ h, const float* __restrict__ W,
    const float* __restrict__ a, unsigned short* __restrict__ whb,
    float* __restrict__ wh1, float* __restrict__ wh2) {
  const int t = threadIdx.x;
  const int w = t >> 6, lane = t & 63;     // wave = one row, lane = output dim
  const int r = blockIdx.x * 4 + w;
  const float* hr = h + (size_t)r * DIN;
  const float* Wc = W + lane;
  float a0 = 0.f, a1 = 0.f, a2 = 0.f, a3 = 0.f;
#pragma unroll 4
  for (int k = 0; k < DIN; k += 4) {
    a0 = fmaf(hr[k + 0], Wc[(k + 0) * DOUT], a0);
    a1 = fmaf(hr[k + 1], Wc[(k + 1) * DOUT], a1);
    a2 = fmaf(hr[k + 2], Wc[(k + 2) * DOUT], a2);
    a3 = fmaf(hr[k + 3], Wc[(k + 3) * DOUT], a3);
  }
  float acc = (a0 + a1) + (a2 + a3);
  whb[frag_byte(r, lane) >> 1] = f2bf(acc);
  float d1 = acc * a[lane];
  float d2 = acc * a[DOUT + lane];
#pragma unroll
  for (int m = 32; m >= 1; m >>= 1) {
    d1 += __shfl_xor(d1, m, 64);
    d2 += __shfl_xor(d2, m, 64);
  }
  if (lane == 0) { wh1[r] = d1; wh2[r] = d2; }
}

__global__ __launch_bounds__(256) void k2_attn(
    const int* __restrict__ adj, const unsigned short* __restrict__ whb,
    const float* __restrict__ wh1, const float* __restrict__ wh2,
    float* __restrict__ pacc, float* __restrict__ pl) {
  __shared__ char p_frag[8192];   // [wave][s][lane][i] : byte = w*2048 + s*1024 + lane*16 + i*2
  __shared__ char v_frag[8192];   // [s][n][lane][i]    : byte = s*4096 + n*1024 + lane*16 + i*2
  __shared__ float lred[256];
  const int t = threadIdx.x;
  const int w = t >> 6, lane = t & 63;
  const int rb = blockIdx.x, sp = blockIdx.y;
  const int r0 = rb * 64;
  const int jbase = sp * JCHUNK;
  const int rloc = t >> 2;        // score row 0..63  (== wave w's A-rows for rloc>>4 == w)
  const int cq = t & 3;           // 16-col chunk within the 64-wide tile
  const float wh1r = wh1[r0 + rloc];
  float lacc = 0.f;
  f32x4 acc[4] = {};
  const size_t adjbase = (size_t)(r0 + rloc) * NN + jbase + cq * 16;
  // p-write base: w*2048 | s*1024 | (rloc&15)*16 | i0*2   (s=(cq>>1), i0=4*(cq&1)); +qq*256 per b64
  const int pwbase = (w << 11) | ((cq >> 1) << 10) | ((rloc & 15) << 4) | ((cq & 1) << 3);

  for (int tile = 0; tile < NTILES; ++tile) {
    const int jt = jbase + tile * CTILE;
    // V tile: 8 KB contiguous in global (fragment order) -> regs
    const uint4* vsrc = (const uint4*)(whb + ((size_t)(jt >> 5) << 11));
    uint4 va = vsrc[t];
    uint4 vb = vsrc[t + 256];
    // adj + wh2 for this thread's 16 columns
    const int4* ap = (const int4*)(adj + adjbase + (size_t)tile * CTILE);
    int4 A0 = ap[0], A1 = ap[1], A2 = ap[2], A3 = ap[3];
    const float4* w2p = (const float4*)(wh2 + jt + cq * 16);
    float4 F0 = w2p[0], F1 = w2p[1], F2 = w2p[2], F3 = w2p[3];

    unsigned int pk[8];
    {
      const int av[16] = {A0.x, A0.y, A0.z, A0.w, A1.x, A1.y, A1.z, A1.w,
                          A2.x, A2.y, A2.z, A2.w, A3.x, A3.y, A3.z, A3.w};
      const float wv[16] = {F0.x, F0.y, F0.z, F0.w, F1.x, F1.y, F1.z, F1.w,
                            F2.x, F2.y, F2.z, F2.w, F3.x, F3.y, F3.z, F3.w};
#pragma unroll
      for (int u = 0; u < 16; u += 2) {
        float s0 = wh1r + wv[u];
        float s1 = wh1r + wv[u + 1];
        s0 = s0 > 0.f ? s0 : 0.2f * s0;
        s1 = s1 > 0.f ? s1 : 0.2f * s1;
        float p0 = av[u] > 0 ? __expf(s0) : 0.f;
        float p1 = av[u + 1] > 0 ? __expf(s1) : 0.f;
        lacc += p0 + p1;
        pk[u >> 1] = (unsigned)f2bf(p0) | ((unsigned)f2bf(p1) << 16);
      }
    }
    __syncthreads();   // previous tile's MFMA reads done
#pragma unroll
    for (int qq = 0; qq < 4; ++qq) {
      uint2 val; val.x = pk[qq * 2]; val.y = pk[qq * 2 + 1];
      *(uint2*)(p_frag + (pwbase | (qq << 8))) = val;
    }
    *(uint4*)(v_frag + t * 16) = va;
    *(uint4*)(v_frag + t * 16 + 4096) = vb;
    __syncthreads();
    // MFMA: A = P[16x32] per wave, B = V[32x64] as 4 n-tiles, 2 K-steps
    short8 af0 = *(const short8*)(p_frag + (w << 11) + (lane << 4));
    short8 af1 = *(const short8*)(p_frag + (w << 11) + 1024 + (lane << 4));
#pragma unroll
    for (int n = 0; n < 4; ++n) {
      short8 b0 = *(const short8*)(v_frag + (n << 10) + (lane << 4));
      short8 b1 = *(const short8*)(v_frag + 4096 + (n << 10) + (lane << 4));
      acc[n] = __builtin_amdgcn_mfma_f32_16x16x32_bf16(af0, b0, acc[n], 0, 0, 0);
      acc[n] = __builtin_amdgcn_mfma_f32_16x16x32_bf16(af1, b1, acc[n], 0, 0, 0);
    }
  }
  // reduce l across the 4 threads per row
  lred[t] = lacc;
  __syncthreads();
  if (t < 64) {
    float l = lred[t * 4] + lred[t * 4 + 1] + lred[t * 4 + 2] + lred[t * 4 + 3];
    pl[(size_t)sp * NN + r0 + t] = l;
  }
  // write acc partials; C/D layout (verified): col = lane&15, row = (lane>>4)*4 + reg
  float* pa = pacc + (size_t)sp * (NN * DOUT);
#pragma unroll
  for (int n = 0; n < 4; ++n) {
#pragma unroll
    for (int j = 0; j < 4; ++j) {
      int row = r0 + w * 16 + ((lane >> 4) << 2) + j;
      int col = (n << 4) | (lane & 15);
      pa[(size_t)row * DOUT + col] = acc[n][j];
    }
  }
}

__global__ __launch_bounds__(256) void k3_out(
    const float* __restrict__ pacc, const float* __restrict__ pl,
    float* __restrict__ out) {
  const int idx = blockIdx.x * 256 + threadIdx.x;
  const int r = idx >> 6;
  float a = 0.f, l = 0.f;
#pragma unroll
  for (int sp = 0; sp < NSPLIT; ++sp) {
    a += pacc[(size_t)sp * (NN * DOUT) + idx];
    l += pl[(size_t)sp * NN + r];
  }
  float hp = a / l;
  out[idx] = hp > 0.f ? hp : (expf(hp) - 1.f);
}

extern "C" void kernel_launch(void* const* d_in, const int* in_sizes, int n_in,
                              void* d_out, int out_size, void* d_ws, size_t ws_size,
                              hipStream_t stream) {
  const float* h = (const float*)d_in[0];
  const float* W = (const float*)d_in[1];
  const float* a = (const float*)d_in[2];
  const int* adj = (const int*)d_in[3];
  float* out = (float*)d_out;
  char* ws = (char*)d_ws;
  unsigned short* whb = (unsigned short*)ws;                    // 1 MB  (bf16 Wh, frag order)
  float* wh1 = (float*)(ws + (1 << 20));                        // 32 KB
  float* wh2 = (float*)(ws + (1 << 20) + (32 << 10));           // 32 KB
  float* pl  = (float*)(ws + (1 << 20) + (64 << 10));           // 256 KB
  float* pacc = (float*)(ws + (1 << 20) + (64 << 10) + (256 << 10)); // 16 MB
  k1_wh<<<NN / 4, 256, 0, stream>>>(h, W, a, whb, wh1, wh2);
  dim3 g2(NN / 64, NSPLIT);
  k2_attn<<<g2, 256, 0, stream>>>(adj, whb, wh1, wh2, pacc, pl);
  k3_out<<<(NN * DOUT) / 256, 256, 0, stream>>>(pacc, pl, out);
}

// Round 3
// 433.252 us; speedup vs baseline: 1.1399x; 1.1399x over previous
//
#include <hip/hip_runtime.h>
#include <stdint.h>

// GAT layer, N=8192, D_IN=512, D_OUT=64.
// k1: Wh = h@W (f32, fully vectorized), stores Wh bf16 in MFMA-fragment order + wh1/wh2 (f32).
// k2: one block = 16 rows x all 8192 j. Scores computed straight into A-fragment registers
//     (no LDS / no barriers in main loop), V fragments loaded direct from global (L2-hot),
//     2-deep register pipeline over 32-j chunks, full softmax + elu fused; writes final out.
// Softmax shift-invariance: s = wh1[i]+wh2[j] bounded (|s|<~8 before leakyrelu) so
// unnormalized exp(s) is safe in f32; masked entries contribute p=0.

constexpr int NN = 8192;
constexpr int DIN = 512;
constexpr int DOUT = 64;

typedef __attribute__((ext_vector_type(4))) float f32x4;
typedef __attribute__((ext_vector_type(8))) short short8;
typedef int int32x4 __attribute__((ext_vector_type(4)));

__device__ __forceinline__ unsigned short f2bf(float x) {
  union { float f; uint32_t u; } v; v.f = x;
  return (unsigned short)((v.u + 0x7fffu + ((v.u >> 16) & 1u)) >> 16);
}

// fragment-order byte offset for element (k-row c, col d); k-map shared by A and B:
// k = g*4 + (i&3) + 16*(i>>2), lane16 = g*16 + (d&15).
__device__ __forceinline__ int frag_byte(int c, int d) {
  int g = (c >> 2) & 3;
  int i = (c & 3) | (((c >> 4) & 1) << 2);
  return ((c >> 5) << 12) | ((d >> 4) << 10) | (((g << 4) | (d & 15)) << 4) | (i << 1);
}

__global__ __launch_bounds__(256) void k1_wh(
    const float* __restrict__ h, const float* __restrict__ W,
    const float* __restrict__ a, unsigned short* __restrict__ whb,
    float* __restrict__ wh1, float* __restrict__ wh2) {
  const int t = threadIdx.x, w = t >> 6, l = t & 63;
  const int r = blockIdx.x * 4 + w;
  const int q = l >> 4, cg = l & 15;          // lane = (k-quarter, col-quad)
  const float* hr = h + (size_t)r * DIN + q * 128;
  const float* Wp = W + (size_t)(q * 128) * DOUT + cg * 4;
  float ax = 0.f, ay = 0.f, az = 0.f, aw = 0.f;
#pragma unroll 4
  for (int kk = 0; kk < 32; ++kk) {
    float4 h4 = *(const float4*)(hr + kk * 4);
    const float* wr = Wp + (size_t)kk * 4 * DOUT;
    float4 w0 = *(const float4*)(wr);
    float4 w1 = *(const float4*)(wr + DOUT);
    float4 w2 = *(const float4*)(wr + 2 * DOUT);
    float4 w3 = *(const float4*)(wr + 3 * DOUT);
    ax = fmaf(h4.x, w0.x, ax); ay = fmaf(h4.x, w0.y, ay); az = fmaf(h4.x, w0.z, az); aw = fmaf(h4.x, w0.w, aw);
    ax = fmaf(h4.y, w1.x, ax); ay = fmaf(h4.y, w1.y, ay); az = fmaf(h4.y, w1.z, az); aw = fmaf(h4.y, w1.w, aw);
    ax = fmaf(h4.z, w2.x, ax); ay = fmaf(h4.z, w2.y, ay); az = fmaf(h4.z, w2.z, az); aw = fmaf(h4.z, w2.w, aw);
    ax = fmaf(h4.w, w3.x, ax); ay = fmaf(h4.w, w3.y, ay); az = fmaf(h4.w, w3.z, az); aw = fmaf(h4.w, w3.w, aw);
  }
  // reduce over the 4 k-quarters (xor lanes 16, 32)
  ax += __shfl_xor(ax, 16, 64); ax += __shfl_xor(ax, 32, 64);
  ay += __shfl_xor(ay, 16, 64); ay += __shfl_xor(ay, 32, 64);
  az += __shfl_xor(az, 16, 64); az += __shfl_xor(az, 32, 64);
  aw += __shfl_xor(aw, 16, 64); aw += __shfl_xor(aw, 32, 64);
  // wh1/wh2 dot with a
  float4 a1v = *(const float4*)(a + cg * 4);
  float4 a2v = *(const float4*)(a + DOUT + cg * 4);
  float d1 = ax * a1v.x + ay * a1v.y + az * a1v.z + aw * a1v.w;
  float d2 = ax * a2v.x + ay * a2v.y + az * a2v.z + aw * a2v.w;
#pragma unroll
  for (int m = 8; m >= 1; m >>= 1) { d1 += __shfl_xor(d1, m, 64); d2 += __shfl_xor(d2, m, 64); }
  if (l == 0) { wh1[r] = d1; wh2[r] = d2; }
  if (l < 16) {
    whb[frag_byte(r, cg * 4 + 0) >> 1] = f2bf(ax);
    whb[frag_byte(r, cg * 4 + 1) >> 1] = f2bf(ay);
    whb[frag_byte(r, cg * 4 + 2) >> 1] = f2bf(az);
    whb[frag_byte(r, cg * 4 + 3) >> 1] = f2bf(aw);
  }
}

struct KRegs {
  int32x4 a0, a1;
  float4 f0, f1;
  uint4 v0, v1, v2, v3;
};

__global__ __launch_bounds__(256, 2) void k2_attn(
    const int* __restrict__ adj, const unsigned short* __restrict__ whb,
    const float* __restrict__ wh1, const float* __restrict__ wh2,
    float* __restrict__ out) {
  __shared__ float accs[4][16][64];
  __shared__ float lsum[4][16];
  const int t = threadIdx.x, w = t >> 6, l = t & 63;
  const int r0 = blockIdx.x * 16;
  const int row = l & 15, g = l >> 4;
  const float wh1r = wh1[r0 + row];
  const int jb = w * 2048 + 4 * g;  // wave-private 2048-j stripe; lane j-run base
  const int32x4* adjp = (const int32x4*)(adj + (size_t)(r0 + row) * NN + jb);
  const float4* w2p = (const float4*)(wh2 + jb);
  const uint4* vp = (const uint4*)whb + (size_t)w * 64 * 256 + l;
  f32x4 acc0 = {}, acc1 = {}, acc2 = {}, acc3 = {};
  float lacc = 0.f;

#define LOADC(R, c) do { \
    R.a0 = __builtin_nontemporal_load(adjp + (c) * 8); \
    R.a1 = __builtin_nontemporal_load(adjp + (c) * 8 + 4); \
    R.f0 = w2p[(c) * 8]; R.f1 = w2p[(c) * 8 + 4]; \
    R.v0 = vp[(c) * 256]; R.v1 = vp[(c) * 256 + 64]; \
    R.v2 = vp[(c) * 256 + 128]; R.v3 = vp[(c) * 256 + 192]; \
  } while (0)

#define SC(pv, av, fv) { float s_ = wh1r + (fv); s_ = fmaxf(s_, 0.2f * s_); \
                         float e_ = __expf(s_); pv = ((av) > 0) ? e_ : 0.f; }

#define COMP(R) do { \
    float p0, p1, p2, p3, p4, p5, p6, p7; \
    SC(p0, R.a0.x, R.f0.x) SC(p1, R.a0.y, R.f0.y) SC(p2, R.a0.z, R.f0.z) SC(p3, R.a0.w, R.f0.w) \
    SC(p4, R.a1.x, R.f1.x) SC(p5, R.a1.y, R.f1.y) SC(p6, R.a1.z, R.f1.z) SC(p7, R.a1.w, R.f1.w) \
    lacc += ((p0 + p1) + (p2 + p3)) + ((p4 + p5) + (p6 + p7)); \
    union { uint32_t u[4]; short8 s; } af; \
    af.u[0] = f2bf(p0) | ((uint32_t)f2bf(p1) << 16); \
    af.u[1] = f2bf(p2) | ((uint32_t)f2bf(p3) << 16); \
    af.u[2] = f2bf(p4) | ((uint32_t)f2bf(p5) << 16); \
    af.u[3] = f2bf(p6) | ((uint32_t)f2bf(p7) << 16); \
    union { uint4 q; short8 s; } b0, b1, b2, b3; \
    b0.q = R.v0; b1.q = R.v1; b2.q = R.v2; b3.q = R.v3; \
    acc0 = __builtin_amdgcn_mfma_f32_16x16x32_bf16(af.s, b0.s, acc0, 0, 0, 0); \
    acc1 = __builtin_amdgcn_mfma_f32_16x16x32_bf16(af.s, b1.s, acc1, 0, 0, 0); \
    acc2 = __builtin_amdgcn_mfma_f32_16x16x32_bf16(af.s, b2.s, acc2, 0, 0, 0); \
    acc3 = __builtin_amdgcn_mfma_f32_16x16x32_bf16(af.s, b3.s, acc3, 0, 0, 0); \
  } while (0)

  KRegs A, B;
  LOADC(A, 0);
  LOADC(B, 1);
  for (int c = 0; c + 2 < 64; c += 2) {
    COMP(A); LOADC(A, c + 2);
    COMP(B); LOADC(B, c + 3);
  }
  COMP(A);
  COMP(B);

  // denominator: reduce over the 4 j-run groups within the wave
  lacc += __shfl_xor(lacc, 16, 64);
  lacc += __shfl_xor(lacc, 32, 64);
  if (l < 16) lsum[w][l] = lacc;
  // stash acc; C/D layout: row = (lane>>4)*4 + reg, col = n*16 + (lane&15)
  {
    const int rb = (l >> 4) * 4, cl = l & 15;
#define WACC(an, n) { accs[w][rb + 0][(n)*16 + cl] = an[0]; accs[w][rb + 1][(n)*16 + cl] = an[1]; \
                      accs[w][rb + 2][(n)*16 + cl] = an[2]; accs[w][rb + 3][(n)*16 + cl] = an[3]; }
    WACC(acc0, 0) WACC(acc1, 1) WACC(acc2, 2) WACC(acc3, 3)
#undef WACC
  }
  __syncthreads();
  // sum the 4 wave-stripes, normalize, elu, store
  {
    const int rr = t >> 4, dq = (t & 15) * 4;
    float4 s0 = *(const float4*)&accs[0][rr][dq];
    float4 s1 = *(const float4*)&accs[1][rr][dq];
    float4 s2 = *(const float4*)&accs[2][rr][dq];
    float4 s3 = *(const float4*)&accs[3][rr][dq];
    float L = (lsum[0][rr] + lsum[1][rr]) + (lsum[2][rr] + lsum[3][rr]);
    float inv = 1.0f / L;
    float4 o;
    float v;
    v = (s0.x + s1.x + s2.x + s3.x) * inv; o.x = v > 0.f ? v : __expf(v) - 1.f;
    v = (s0.y + s1.y + s2.y + s3.y) * inv; o.y = v > 0.f ? v : __expf(v) - 1.f;
    v = (s0.z + s1.z + s2.z + s3.z) * inv; o.z = v > 0.f ? v : __expf(v) - 1.f;
    v = (s0.w + s1.w + s2.w + s3.w) * inv; o.w = v > 0.f ? v : __expf(v) - 1.f;
    *(float4*)(out + (size_t)(r0 + rr) * DOUT + dq) = o;
  }
#undef LOADC
#undef SC
#undef COMP
}

extern "C" void kernel_launch(void* const* d_in, const int* in_sizes, int n_in,
                              void* d_out, int out_size, void* d_ws, size_t ws_size,
                              hipStream_t stream) {
  const float* h = (const float*)d_in[0];
  const float* W = (const float*)d_in[1];
  const float* a = (const float*)d_in[2];
  const int* adj = (const int*)d_in[3];
  float* out = (float*)d_out;
  char* ws = (char*)d_ws;
  unsigned short* whb = (unsigned short*)ws;            // 1 MB bf16 Wh, fragment order
  float* wh1 = (float*)(ws + (1 << 20));                // 32 KB
  float* wh2 = (float*)(ws + (1 << 20) + (32 << 10));   // 32 KB
  k1_wh<<<NN / 4, 256, 0, stream>>>(h, W, a, whb, wh1, wh2);
  k2_attn<<<NN / 16, 256, 0, stream>>>(adj, whb, wh1, wh2, out);
}

// Round 4
// 423.322 us; speedup vs baseline: 1.1666x; 1.0235x over previous
//
#include <hip/hip_runtime.h>
#include <hip/hip_bf16.h>
#include <stdint.h>

// GAT layer, N=8192, D_IN=512, D_OUT=64.
// k1: Wh = h@W (f32). 4 rows/wave share W loads (W L2-traffic 1GB -> 256MB). Stores Wh bf16
//     in MFMA fragment order (whb) + wh1/wh2 (f32).
// k2: one block = 16 rows x all 8192 j, 8 waves x 1024-j stripes (4 waves/SIMD for latency
//     hiding). Scores straight into A-fragment registers, V fragments direct from L2-hot whb,
//     2-deep register pipeline, no LDS/barriers in main loop; full softmax + elu fused.
// Softmax shift-invariance: s bounded (|s|<~8) so unnormalized exp is safe in f32.
// NOTE (journal): dur_us carries ~333us fixed harness overhead (two ~165us 1GiB d_ws poison
// fills visible as top dispatches); kernel-side budget this round: ~100us -> target ~60us.

constexpr int NN = 8192;
constexpr int DIN = 512;
constexpr int DOUT = 64;

typedef __attribute__((ext_vector_type(4))) float f32x4;
typedef __attribute__((ext_vector_type(8))) short short8;
typedef int int32x4 __attribute__((ext_vector_type(4)));

__device__ __forceinline__ unsigned short f2bf(float x) {
  union { float f; uint32_t u; } v; v.f = x;
  return (unsigned short)((v.u + 0x7fffu + ((v.u >> 16) & 1u)) >> 16);
}

// fragment-order byte offset for element (k-row c, col d); k-map shared by A and B:
// k = g*4 + (i&3) + 16*(i>>2), lane16 = g*16 + (d&15).
__device__ __forceinline__ int frag_byte(int c, int d) {
  int g = (c >> 2) & 3;
  int i = (c & 3) | (((c >> 4) & 1) << 2);
  return ((c >> 5) << 12) | ((d >> 4) << 10) | (((g << 4) | (d & 15)) << 4) | (i << 1);
}

__global__ __launch_bounds__(256) void k1_wh(
    const float* __restrict__ h, const float* __restrict__ W,
    const float* __restrict__ a, unsigned short* __restrict__ whb,
    float* __restrict__ wh1, float* __restrict__ wh2) {
  const int t = threadIdx.x, w = t >> 6, l = t & 63;
  const int r0 = blockIdx.x * 16 + w * 4;     // 4 rows per wave
  const int q = l >> 4, cg = l & 15;          // lane = (k-quarter, col-quad)
  const float* h0 = h + (size_t)r0 * DIN + q * 128;
  const float* Wp = W + (size_t)(q * 128) * DOUT + cg * 4;
  f32x4 acc[4] = {};
#pragma unroll 4
  for (int kk = 0; kk < 32; ++kk) {
    const float* wr = Wp + (size_t)kk * 4 * DOUT;
    float4 w0 = *(const float4*)(wr);
    float4 w1 = *(const float4*)(wr + DOUT);
    float4 w2 = *(const float4*)(wr + 2 * DOUT);
    float4 w3 = *(const float4*)(wr + 3 * DOUT);
#pragma unroll
    for (int r = 0; r < 4; ++r) {
      float4 h4 = *(const float4*)(h0 + (size_t)r * DIN + kk * 4);
      acc[r][0] = fmaf(h4.x, w0.x, acc[r][0]); acc[r][1] = fmaf(h4.x, w0.y, acc[r][1]);
      acc[r][2] = fmaf(h4.x, w0.z, acc[r][2]); acc[r][3] = fmaf(h4.x, w0.w, acc[r][3]);
      acc[r][0] = fmaf(h4.y, w1.x, acc[r][0]); acc[r][1] = fmaf(h4.y, w1.y, acc[r][1]);
      acc[r][2] = fmaf(h4.y, w1.z, acc[r][2]); acc[r][3] = fmaf(h4.y, w1.w, acc[r][3]);
      acc[r][0] = fmaf(h4.z, w2.x, acc[r][0]); acc[r][1] = fmaf(h4.z, w2.y, acc[r][1]);
      acc[r][2] = fmaf(h4.z, w2.z, acc[r][2]); acc[r][3] = fmaf(h4.z, w2.w, acc[r][3]);
      acc[r][0] = fmaf(h4.w, w3.x, acc[r][0]); acc[r][1] = fmaf(h4.w, w3.y, acc[r][1]);
      acc[r][2] = fmaf(h4.w, w3.z, acc[r][2]); acc[r][3] = fmaf(h4.w, w3.w, acc[r][3]);
    }
  }
  // reduce over the 4 k-quarters
#pragma unroll
  for (int r = 0; r < 4; ++r)
#pragma unroll
    for (int cpt = 0; cpt < 4; ++cpt) {
      float v = acc[r][cpt];
      v += __shfl_xor(v, 16, 64);
      v += __shfl_xor(v, 32, 64);
      acc[r][cpt] = v;
    }
  float4 a1v = *(const float4*)(a + cg * 4);
  float4 a2v = *(const float4*)(a + DOUT + cg * 4);
#pragma unroll
  for (int r = 0; r < 4; ++r) {
    float d1 = acc[r][0] * a1v.x + acc[r][1] * a1v.y + acc[r][2] * a1v.z + acc[r][3] * a1v.w;
    float d2 = acc[r][0] * a2v.x + acc[r][1] * a2v.y + acc[r][2] * a2v.z + acc[r][3] * a2v.w;
#pragma unroll
    for (int m = 8; m >= 1; m >>= 1) { d1 += __shfl_xor(d1, m, 64); d2 += __shfl_xor(d2, m, 64); }
    if (l == 0) { wh1[r0 + r] = d1; wh2[r0 + r] = d2; }
    if (l < 16) {
      whb[frag_byte(r0 + r, cg * 4 + 0) >> 1] = f2bf(acc[r][0]);
      whb[frag_byte(r0 + r, cg * 4 + 1) >> 1] = f2bf(acc[r][1]);
      whb[frag_byte(r0 + r, cg * 4 + 2) >> 1] = f2bf(acc[r][2]);
      whb[frag_byte(r0 + r, cg * 4 + 3) >> 1] = f2bf(acc[r][3]);
    }
  }
}

struct KRegs {
  int32x4 a0, a1;
  float4 f0, f1;
  uint4 v0, v1, v2, v3;
};

__global__ __launch_bounds__(512, 4) void k2_attn(
    const int* __restrict__ adj, const unsigned short* __restrict__ whb,
    const float* __restrict__ wh1, const float* __restrict__ wh2,
    float* __restrict__ out) {
  __shared__ float accs[8][16][64];
  __shared__ float lsum[8][16];
  const int t = threadIdx.x, w = t >> 6, l = t & 63;
  const int r0 = blockIdx.x * 16;
  const int row = l & 15, g = l >> 4;
  const float wh1r = wh1[r0 + row];
  const int jb = w * 1024 + 4 * g;  // wave-private 1024-j stripe; lane j-run base
  const int32x4* adjp = (const int32x4*)(adj + (size_t)(r0 + row) * NN + jb);
  const float4* w2p = (const float4*)(wh2 + jb);
  const uint4* vp = (const uint4*)whb + (size_t)w * 8192 + l;  // w*128KB stripe of whb
  f32x4 acc0 = {}, acc1 = {}, acc2 = {}, acc3 = {};
  float lacc = 0.f;

#define LOADC(R, c) do { \
    R.a0 = __builtin_nontemporal_load(adjp + (c) * 8); \
    R.a1 = __builtin_nontemporal_load(adjp + (c) * 8 + 4); \
    R.f0 = w2p[(c) * 8]; R.f1 = w2p[(c) * 8 + 4]; \
    R.v0 = vp[(c) * 256]; R.v1 = vp[(c) * 256 + 64]; \
    R.v2 = vp[(c) * 256 + 128]; R.v3 = vp[(c) * 256 + 192]; \
  } while (0)

#define SC(pv, av, fv) { float s_ = wh1r + (fv); s_ = fmaxf(s_, 0.2f * s_); \
                         float e_ = __expf(s_); pv = ((av) > 0) ? e_ : 0.f; }

#define PK2(lo, hi) ({ __hip_bfloat162 b_ = __float22bfloat162_rn(float2{(lo), (hi)}); \
                       *(uint32_t*)&b_; })

#define COMP(R) do { \
    float p0, p1, p2, p3, p4, p5, p6, p7; \
    SC(p0, R.a0.x, R.f0.x) SC(p1, R.a0.y, R.f0.y) SC(p2, R.a0.z, R.f0.z) SC(p3, R.a0.w, R.f0.w) \
    SC(p4, R.a1.x, R.f1.x) SC(p5, R.a1.y, R.f1.y) SC(p6, R.a1.z, R.f1.z) SC(p7, R.a1.w, R.f1.w) \
    lacc += ((p0 + p1) + (p2 + p3)) + ((p4 + p5) + (p6 + p7)); \
    union { uint32_t u[4]; short8 s; } af; \
    af.u[0] = PK2(p0, p1); af.u[1] = PK2(p2, p3); \
    af.u[2] = PK2(p4, p5); af.u[3] = PK2(p6, p7); \
    union { uint4 q; short8 s; } b0, b1, b2, b3; \
    b0.q = R.v0; b1.q = R.v1; b2.q = R.v2; b3.q = R.v3; \
    acc0 = __builtin_amdgcn_mfma_f32_16x16x32_bf16(af.s, b0.s, acc0, 0, 0, 0); \
    acc1 = __builtin_amdgcn_mfma_f32_16x16x32_bf16(af.s, b1.s, acc1, 0, 0, 0); \
    acc2 = __builtin_amdgcn_mfma_f32_16x16x32_bf16(af.s, b2.s, acc2, 0, 0, 0); \
    acc3 = __builtin_amdgcn_mfma_f32_16x16x32_bf16(af.s, b3.s, acc3, 0, 0, 0); \
  } while (0)

  KRegs A, B;
  LOADC(A, 0);
  LOADC(B, 1);
  for (int c = 0; c + 2 < 32; c += 2) {
    COMP(A); LOADC(A, c + 2);
    COMP(B); LOADC(B, c + 3);
  }
  COMP(A);
  COMP(B);

  // denominator: reduce over the 4 j-run groups within the wave
  lacc += __shfl_xor(lacc, 16, 64);
  lacc += __shfl_xor(lacc, 32, 64);
  if (l < 16) lsum[w][l] = lacc;
  // stash acc; C/D layout: row = (lane>>4)*4 + reg, col = n*16 + (lane&15)
  {
    const int rb = (l >> 4) * 4, cl = l & 15;
#define WACC(an, n) { accs[w][rb + 0][(n)*16 + cl] = an[0]; accs[w][rb + 1][(n)*16 + cl] = an[1]; \
                      accs[w][rb + 2][(n)*16 + cl] = an[2]; accs[w][rb + 3][(n)*16 + cl] = an[3]; }
    WACC(acc0, 0) WACC(acc1, 1) WACC(acc2, 2) WACC(acc3, 3)
#undef WACC
  }
  __syncthreads();
  // sum the 8 wave-stripes, normalize, elu, store
  if (t < 256) {
    const int rr = t >> 4, dq = (t & 15) * 4;
    float sx = 0.f, sy = 0.f, sz = 0.f, sw = 0.f, L = 0.f;
#pragma unroll
    for (int ws = 0; ws < 8; ++ws) {
      float4 sv = *(const float4*)&accs[ws][rr][dq];
      sx += sv.x; sy += sv.y; sz += sv.z; sw += sv.w;
      L += lsum[ws][rr];
    }
    float inv = 1.0f / L;
    float4 o;
    float v;
    v = sx * inv; o.x = v > 0.f ? v : __expf(v) - 1.f;
    v = sy * inv; o.y = v > 0.f ? v : __expf(v) - 1.f;
    v = sz * inv; o.z = v > 0.f ? v : __expf(v) - 1.f;
    v = sw * inv; o.w = v > 0.f ? v : __expf(v) - 1.f;
    *(float4*)(out + (size_t)(r0 + rr) * DOUT + dq) = o;
  }
#undef LOADC
#undef SC
#undef PK2
#undef COMP
}

extern "C" void kernel_launch(void* const* d_in, const int* in_sizes, int n_in,
                              void* d_out, int out_size, void* d_ws, size_t ws_size,
                              hipStream_t stream) {
  const float* h = (const float*)d_in[0];
  const float* W = (const float*)d_in[1];
  const float* a = (const float*)d_in[2];
  const int* adj = (const int*)d_in[3];
  float* out = (float*)d_out;
  char* ws = (char*)d_ws;
  unsigned short* whb = (unsigned short*)ws;            // 1 MB bf16 Wh, fragment order
  float* wh1 = (float*)(ws + (1 << 20));                // 32 KB
  float* wh2 = (float*)(ws + (1 << 20) + (32 << 10));   // 32 KB
  k1_wh<<<NN / 16, 256, 0, stream>>>(h, W, a, whb, wh1, wh2);
  k2_attn<<<NN / 16, 512, 0, stream>>>(adj, whb, wh1, wh2, out);
}